// Round 5
// baseline (273.582 us; speedup 1.0000x reference)
//
#include <hip/hip_runtime.h>
#include <cstdint>
#include <cstddef>

// Problem constants (fixed by the reference)
#define B_  2
#define T_  2048
#define D_  1024
#define H_  16
#define DH_ 64
#define M_  (B_*T_)   // 4096 rows when [B,T,D] flattened

typedef __bf16 bf16x8 __attribute__((ext_vector_type(8)));   // MFMA A/B frag (4 VGPRs)
typedef float  f32x4  __attribute__((ext_vector_type(4)));   // MFMA C/D frag
typedef unsigned short us4 __attribute__((ext_vector_type(4)));
typedef unsigned short us8 __attribute__((ext_vector_type(8)));
typedef unsigned short ushort_t;

__device__ __forceinline__ unsigned short f32_to_bf16_rne(float f) {
    unsigned u = __builtin_bit_cast(unsigned, f);
    u += 0x7FFFu + ((u >> 16) & 1u);
    return (unsigned short)(u >> 16);
}

// pack two f32 -> two bf16 in one u32 (round-half-up; ties differ from RNE only
// on exact .5 ULP — negligible here). 2 adds + 1 v_perm_b32.
__device__ __forceinline__ unsigned pack_bf16_2(float f0, float f1) {
    unsigned a = __builtin_bit_cast(unsigned, f0) + 0x8000u;
    unsigned b = __builtin_bit_cast(unsigned, f1) + 0x8000u;
    return __builtin_amdgcn_perm(b, a, 0x07060302u);   // (hi16(b)<<16) | hi16(a)
}

// async global->LDS, 16 B per lane (GEMM staging only).
__device__ __forceinline__ void async16(const void* g, void* l) {
    __builtin_amdgcn_global_load_lds(
        (const __attribute__((address_space(1))) unsigned int*)(uintptr_t)g,
        (__attribute__((address_space(3))) unsigned int*)(uintptr_t)l, 16, 0, 0);
}

// ---------------- fp32 -> bf16 conversion (single launch, 7 tensors) ----------------
__global__ __launch_bounds__(256) void cvt_all(
    const float* __restrict__ i0, const float* __restrict__ i1, const float* __restrict__ i2,
    const float* __restrict__ i3, const float* __restrict__ i4, const float* __restrict__ i5,
    const float* __restrict__ i6,
    ushort_t* __restrict__ o0, ushort_t* __restrict__ o1, ushort_t* __restrict__ o2,
    ushort_t* __restrict__ o3, ushort_t* __restrict__ o4, ushort_t* __restrict__ o5,
    ushort_t* __restrict__ o6) {
    const int y = blockIdx.y;
    const float* in = y == 0 ? i0 : y == 1 ? i1 : y == 2 ? i2 : y == 3 ? i3
                    : y == 4 ? i4 : y == 5 ? i5 : i6;
    ushort_t* out  = y == 0 ? o0 : y == 1 ? o1 : y == 2 ? o2 : y == 3 ? o3
                    : y == 4 ? o4 : y == 5 ? o5 : o6;
    const int n = (y < 3) ? (M_ * D_) : (D_ * D_);
    int i = (blockIdx.x * 256 + threadIdx.x) * 4;
    if (i >= n) return;
    float4 f = *reinterpret_cast<const float4*>(in + i);
    unsigned lo = pack_bf16_2(f.x, f.y);
    unsigned hi = pack_bf16_2(f.z, f.w);
    *reinterpret_cast<unsigned long long*>(out + i) =
        (unsigned long long)lo | ((unsigned long long)hi << 32);
}

// ---------------- NT GEMM mainloop: BK=64, swizzled staging, 128x128 tile ----------------
__device__ __forceinline__ void gemm_mainloop(const ushort_t* __restrict__ A,
                                              const ushort_t* __restrict__ W,
                                              ushort_t* As, ushort_t* Bs,
                                              int m0, int n0, f32x4 acc[4][4]) {
    const int tid  = threadIdx.x;
    const int lc   = tid & 15;
    const int quad = (tid >> 4) & 3;
    const int wave = tid >> 6;
    const int wm = (wave >> 1) * 64, wn = (wave & 1) * 64;
    const int sw = lc & 7;   // row-derived swizzle (row&7 == lc&7 for frag rows)

    const f32x4 fzero = {0.f, 0.f, 0.f, 0.f};
#pragma unroll
    for (int mt = 0; mt < 4; ++mt)
#pragma unroll
        for (int nt = 0; nt < 4; ++nt) acc[mt][nt] = fzero;

    for (int kk = 0; kk < D_; kk += 64) {
        __syncthreads();
#pragma unroll
        for (int i = 0; i < 4; ++i) {
            const int j = i * 256 + tid;           // 1024 chunks of 16 B per tile
            const int r = j >> 3, c = (j & 7) ^ (r & 7);
            async16(A + (size_t)(m0 + r) * D_ + kk + c * 8, As + j * 8);
            async16(W + (size_t)(n0 + r) * D_ + kk + c * 8, Bs + j * 8);
        }
        __syncthreads();   // staging complete
#pragma unroll
        for (int ks = 0; ks < 2; ++ks) {
            bf16x8 af[4], bw[4];
#pragma unroll
            for (int mt = 0; mt < 4; ++mt)
                af[mt] = *reinterpret_cast<const bf16x8*>(
                    As + (wm + mt * 16 + lc) * 64 + (((ks * 4 + quad) ^ sw) * 8));
#pragma unroll
            for (int nt = 0; nt < 4; ++nt)
                bw[nt] = *reinterpret_cast<const bf16x8*>(
                    Bs + (wn + nt * 16 + lc) * 64 + (((ks * 4 + quad) ^ sw) * 8));
#pragma unroll
            for (int mt = 0; mt < 4; ++mt)
#pragma unroll
                for (int nt = 0; nt < 4; ++nt)
                    acc[mt][nt] = __builtin_amdgcn_mfma_f32_16x16x32_bf16(af[mt], bw[nt], acc[mt][nt], 0, 0, 0);
        }
    }
}

// Fused Q/K/V projection: grid (8, 32, 3). XCD-local remap.
__global__ __launch_bounds__(256, 3) void gemm_qkv(
    const ushort_t* __restrict__ qb, const ushort_t* __restrict__ kb, const ushort_t* __restrict__ vb,
    const ushort_t* __restrict__ wqb, const ushort_t* __restrict__ wkb, const ushort_t* __restrict__ wvb,
    ushort_t* __restrict__ qhb, ushort_t* __restrict__ khb, ushort_t* __restrict__ vtb) {
    __shared__ __align__(16) ushort_t As[128 * 64];
    __shared__ __align__(16) ushort_t Bs[128 * 64];
    __shared__ __align__(16) ushort_t Ts[4][16 * 80];   // per-wave epilogue relayout

    const int z = blockIdx.z;
    const ushort_t* A = z == 0 ? qb : z == 1 ? kb : vb;
    const ushort_t* W = z == 0 ? wqb : z == 1 ? wkb : wvb;
    const int yt = blockIdx.x + 8 * (blockIdx.y >> 3);   // A-tile (XCD-local)
    const int xt = blockIdx.y & 7;                       // W-col tile
    const int m0 = yt * 128, n0 = xt * 128;

    f32x4 acc[4][4];
    gemm_mainloop(A, W, As, Bs, m0, n0, acc);

    const int tid = threadIdx.x, lane = tid & 63, lc = tid & 15;
    const int quad = (tid >> 4) & 3, wave = tid >> 6;
    const int wm = (wave >> 1) * 64, wn = (wave & 1) * 64;
    const int mG = m0 + wm;
    const int bb = mG >> 11, t0 = mG & (T_ - 1);
    const int hh = (n0 + wn) >> 6;   // wave n-range = exactly one head

    if (z < 2) {
        ushort_t* outp = (z == 0 ? qhb : khb) + ((size_t)bb * H_ + hh) * T_ * DH_;
#pragma unroll
        for (int mt = 0; mt < 4; ++mt) {
#pragma unroll
            for (int nt = 0; nt < 4; ++nt)
#pragma unroll
                for (int r = 0; r < 4; ++r)
                    Ts[wave][(quad * 4 + r) * 80 + nt * 16 + lc] = f32_to_bf16_rne(acc[mt][nt][r]);
#pragma unroll
            for (int it = 0; it < 2; ++it) {
                const int c = it * 64 + lane;   // 128 chunks of 16 B
                const int row = c >> 3, c8 = c & 7;
                us8 vv = *reinterpret_cast<const us8*>(Ts[wave] + row * 80 + c8 * 8);
                *reinterpret_cast<us8*>(outp + (size_t)(t0 + mt * 16 + row) * DH_ + c8 * 8) = vv;
            }
        }
    } else {
        // V^T store [B,H,DH,T]
        ushort_t* base = vtb + ((size_t)bb * H_ + hh) * DH_ * T_;
#pragma unroll
        for (int mt = 0; mt < 4; ++mt) {
#pragma unroll
            for (int nt = 0; nt < 4; ++nt)
#pragma unroll
                for (int r = 0; r < 4; ++r)
                    Ts[wave][(nt * 16 + lc) * 16 + quad * 4 + r] = f32_to_bf16_rne(acc[mt][nt][r]);
#pragma unroll
            for (int it = 0; it < 2; ++it) {
                const int c = it * 64 + lane;
                const int nl = c >> 1, mh = c & 1;
                us8 vv = *reinterpret_cast<const us8*>(Ts[wave] + c * 8);
                *reinterpret_cast<us8*>(base + (size_t)nl * T_ + t0 + mt * 16 + mh * 8) = vv;
            }
        }
    }
}

// Final projection: 64x128 tiles, grid (8,64) -> 512 blocks (2/CU), fp32 out.
__global__ __launch_bounds__(256, 4) void gemm_wo(const ushort_t* __restrict__ A,
                                                  const ushort_t* __restrict__ W,
                                                  float* __restrict__ out) {
    __shared__ __align__(16) ushort_t As[64 * 64];
    __shared__ __align__(16) ushort_t Bs[128 * 64];
    const int yt = blockIdx.x + 8 * (blockIdx.y >> 3);   // 64 A-tiles, XCD-local
    const int xt = blockIdx.y & 7;
    const int m0 = yt * 64, n0 = xt * 128;

    const int tid = threadIdx.x, lc = tid & 15;
    const int quad = (tid >> 4) & 3, wave = tid >> 6;
    const int wm = (wave >> 1) * 32, wn = (wave & 1) * 64;
    const int sw = lc & 7;

    const f32x4 fzero = {0.f, 0.f, 0.f, 0.f};
    f32x4 acc[2][4];
#pragma unroll
    for (int mt = 0; mt < 2; ++mt)
#pragma unroll
        for (int nt = 0; nt < 4; ++nt) acc[mt][nt] = fzero;

    for (int kk = 0; kk < D_; kk += 64) {
        __syncthreads();
#pragma unroll
        for (int i = 0; i < 2; ++i) {
            const int j = i * 256 + tid;           // 512 chunks (A: 64 rows)
            const int r = j >> 3, c = (j & 7) ^ (r & 7);
            async16(A + (size_t)(m0 + r) * D_ + kk + c * 8, As + j * 8);
        }
#pragma unroll
        for (int i = 0; i < 4; ++i) {
            const int j = i * 256 + tid;           // 1024 chunks (B: 128 rows)
            const int r = j >> 3, c = (j & 7) ^ (r & 7);
            async16(W + (size_t)(n0 + r) * D_ + kk + c * 8, Bs + j * 8);
        }
        __syncthreads();
#pragma unroll
        for (int ks = 0; ks < 2; ++ks) {
            bf16x8 af[2], bw[4];
#pragma unroll
            for (int mt = 0; mt < 2; ++mt)
                af[mt] = *reinterpret_cast<const bf16x8*>(
                    As + (wm + mt * 16 + lc) * 64 + (((ks * 4 + quad) ^ sw) * 8));
#pragma unroll
            for (int nt = 0; nt < 4; ++nt)
                bw[nt] = *reinterpret_cast<const bf16x8*>(
                    Bs + (wn + nt * 16 + lc) * 64 + (((ks * 4 + quad) ^ sw) * 8));
#pragma unroll
            for (int mt = 0; mt < 2; ++mt)
#pragma unroll
                for (int nt = 0; nt < 4; ++nt)
                    acc[mt][nt] = __builtin_amdgcn_mfma_f32_16x16x32_bf16(af[mt], bw[nt], acc[mt][nt], 0, 0, 0);
        }
    }

#pragma unroll
    for (int mt = 0; mt < 2; ++mt)
#pragma unroll
        for (int nt = 0; nt < 4; ++nt)
#pragma unroll
            for (int r = 0; r < 4; ++r) {
                const int m = m0 + wm + mt * 16 + quad * 4 + r;
                const int n = n0 + wn + nt * 16 + lc;
                out[(size_t)m * D_ + n] = acc[mt][nt][r];
            }
}

// ---------------- causal flash attention v5: barrier-free ----------------
// K/V is per-XCD L2-resident (round-4 FETCH evidence) -> skip LDS staging entirely.
// Grid 1024 (XCD-local, qt DESCENDING = LPT queue balancing), block 128 = 2 waves,
// each wave independently owns 32 Q rows; NO __syncthreads anywhere.
// K frags double-buffered in regs (prefetch kt+1 during softmax/PV); V frags loaded
// at iter start, consumed after softmax (~400 cyc of cover).
// K fragment rows are lane-permuted at the GLOBAL address (key = k0+4*lc+ct) so the
// P write is 1 ds_write_b64 per row (packed via v_perm) into natural key order.
__global__ __launch_bounds__(128, 2) void attn5(const ushort_t* __restrict__ Qh,
                                                const ushort_t* __restrict__ Kh,
                                                const ushort_t* __restrict__ Vt,
                                                ushort_t* __restrict__ Ao) {
    __shared__ __align__(16) ushort_t Ps[2][16 * 88];   // per-wave P tile, 5.6 KB total

    const int tid = threadIdx.x, lc = tid & 15;
    const int quad = (tid >> 4) & 3, wave = tid >> 6;   // 0..1

    const int L = blockIdx.x;
    const int xcd = L & 7, s = L >> 3;
    const int bh = xcd + 8 * (s >> 5);     // 4 bh per XCD -> K/V pinned in 4 MB L2
    const int qt = 31 - (s & 31);          // big q-tiles dispatched first (LPT)
    const int bb = bh >> 4, hh = bh & 15;
    const int q0 = qt * 64, nkt = qt + 1;
    const int mbase = q0 + wave * 32;

    const ushort_t* Qp = Qh + (size_t)bh * T_ * DH_;
    const ushort_t* Kp = Kh + (size_t)bh * T_ * DH_;
    const ushort_t* Vp = Vt + (size_t)bh * DH_ * T_;
    const float SC2 = 0.18033688f;   // log2(e)/sqrt(64)
    const f32x4 fzero = {0.f, 0.f, 0.f, 0.f};
    ushort_t* Pw = Ps[wave];

    // Q A-frags (32 rows -> 2 m-tiles), loop-invariant
    bf16x8 aq[2][2];
#pragma unroll
    for (int mt = 0; mt < 2; ++mt) {
        const ushort_t* qrow = Qp + (size_t)(mbase + mt * 16 + lc) * DH_ + quad * 8;
        aq[mt][0] = *reinterpret_cast<const bf16x8*>(qrow);
        aq[mt][1] = *reinterpret_cast<const bf16x8*>(qrow + 32);
    }

    f32x4 o[2][4];
    float lsum[2][4];
#pragma unroll
    for (int mt = 0; mt < 2; ++mt) {
#pragma unroll
        for (int ct = 0; ct < 4; ++ct) o[mt][ct] = fzero;
#pragma unroll
        for (int r = 0; r < 4; ++r) lsum[mt][r] = 0.f;
    }

    bf16x8 bkA[4][2], bkB[4][2], bv[4][2];

    auto loadK = [&](int kt, bf16x8 (&bk)[4][2]) {
#pragma unroll
        for (int ct = 0; ct < 4; ++ct) {
            const ushort_t* kr = Kp + (size_t)(kt * 64 + 4 * lc + ct) * DH_ + quad * 8;
            bk[ct][0] = *reinterpret_cast<const bf16x8*>(kr);
            bk[ct][1] = *reinterpret_cast<const bf16x8*>(kr + 32);
        }
    };
    auto loadV = [&](int kt) {
#pragma unroll
        for (int ct = 0; ct < 4; ++ct) {
            const ushort_t* vr = Vp + (size_t)(ct * 16 + lc) * T_ + kt * 64 + quad * 8;
            bv[ct][0] = *reinterpret_cast<const bf16x8*>(vr);
            bv[ct][1] = *reinterpret_cast<const bf16x8*>(vr + 32);
        }
    };
    auto computeS = [&](bf16x8 (&bk)[4][2], f32x4 (&sc)[2][4]) {
#pragma unroll
        for (int ct = 0; ct < 4; ++ct)
#pragma unroll
            for (int mt = 0; mt < 2; ++mt) {
                sc[mt][ct] = __builtin_amdgcn_mfma_f32_16x16x32_bf16(aq[mt][0], bk[ct][0], fzero, 0, 0, 0);
                sc[mt][ct] = __builtin_amdgcn_mfma_f32_16x16x32_bf16(aq[mt][1], bk[ct][1], sc[mt][ct], 0, 0, 0);
            }
    };
    auto softmaxPV = [&](int kt, f32x4 (&sc)[2][4]) {
        const int k0 = kt * 64;
#pragma unroll
        for (int mt = 0; mt < 2; ++mt) {
            float e[4][4];
            if (kt == qt) {   // only the diagonal tile masks
#pragma unroll
                for (int ct = 0; ct < 4; ++ct) {
                    const int key = k0 + 4 * lc + ct;
#pragma unroll
                    for (int r = 0; r < 4; ++r) {
                        const int row = mbase + mt * 16 + quad * 4 + r;
                        e[ct][r] = (key <= row) ? __builtin_amdgcn_exp2f(sc[mt][ct][r] * SC2) : 0.f;
                    }
                }
            } else {
#pragma unroll
                for (int ct = 0; ct < 4; ++ct)
#pragma unroll
                    for (int r = 0; r < 4; ++r)
                        e[ct][r] = __builtin_amdgcn_exp2f(sc[mt][ct][r] * SC2);
            }
#pragma unroll
            for (int r = 0; r < 4; ++r) {
                lsum[mt][r] += (e[0][r] + e[1][r]) + (e[2][r] + e[3][r]);
                unsigned lo = pack_bf16_2(e[0][r], e[1][r]);
                unsigned hi = pack_bf16_2(e[2][r], e[3][r]);
                *reinterpret_cast<unsigned long long*>(Pw + (quad * 4 + r) * 88 + lc * 4) =
                    (unsigned long long)lo | ((unsigned long long)hi << 32);
            }
            bf16x8 ap0 = *reinterpret_cast<const bf16x8*>(Pw + lc * 88 + quad * 8);
            bf16x8 ap1 = *reinterpret_cast<const bf16x8*>(Pw + lc * 88 + 32 + quad * 8);
#pragma unroll
            for (int ct = 0; ct < 4; ++ct) {
                o[mt][ct] = __builtin_amdgcn_mfma_f32_16x16x32_bf16(ap0, bv[ct][0], o[mt][ct], 0, 0, 0);
                o[mt][ct] = __builtin_amdgcn_mfma_f32_16x16x32_bf16(ap1, bv[ct][1], o[mt][ct], 0, 0, 0);
            }
        }
    };

    // ---- k-loop: 2x manually unrolled for register double-buffering of K ----
    loadK(0, bkA);
    int kt = 0;
    while (true) {
        {   // even step: consume bkA, prefetch into bkB
            loadV(kt);
            f32x4 sc[2][4];
            computeS(bkA, sc);
            if (kt + 1 < nkt) loadK(kt + 1, bkB);
            softmaxPV(kt, sc);
        }
        if (++kt >= nkt) break;
        {   // odd step: consume bkB, prefetch into bkA
            loadV(kt);
            f32x4 sc[2][4];
            computeS(bkB, sc);
            if (kt + 1 < nkt) loadK(kt + 1, bkA);
            softmaxPV(kt, sc);
        }
        if (++kt >= nkt) break;
    }

    // ---- epilogue: per-wave row-sum reduce + store (no cross-wave combine) ----
#pragma unroll
    for (int mt = 0; mt < 2; ++mt) {
        float inv[4];
#pragma unroll
        for (int r = 0; r < 4; ++r) {
            float l = lsum[mt][r];
#pragma unroll
            for (int d = 1; d < 16; d <<= 1) l += __shfl_xor(l, d);
            inv[r] = 1.0f / l;
        }
#pragma unroll
        for (int ct = 0; ct < 4; ++ct)
#pragma unroll
            for (int r = 0; r < 4; ++r) {
                const int row = mbase + mt * 16 + quad * 4 + r;
                Ao[((size_t)bb * T_ + row) * D_ + hh * DH_ + ct * 16 + lc] =
                    f32_to_bf16_rne(o[mt][ct][r] * inv[r]);
            }
    }
}

// ---------------- launch ----------------
extern "C" void kernel_launch(void* const* d_in, const int* in_sizes, int n_in,
                              void* d_out, int out_size, void* d_ws, size_t ws_size,
                              hipStream_t stream) {
    const float* q  = (const float*)d_in[0];
    const float* k  = (const float*)d_in[1];
    const float* v  = (const float*)d_in[2];
    const float* wq = (const float*)d_in[3];
    const float* wk = (const float*)d_in[4];
    const float* wv = (const float*)d_in[5];
    const float* wo = (const float*)d_in[6];

    char* ws = (char*)d_ws;
    size_t off = 0;
    auto alloc = [&](size_t bytes) -> char* {
        char* p = ws + off;
        off += (bytes + 255) & ~(size_t)255;
        return p;
    };
    ushort_t* qb  = (ushort_t*)alloc((size_t)M_ * D_ * 2);
    ushort_t* kb  = (ushort_t*)alloc((size_t)M_ * D_ * 2);
    ushort_t* vb  = (ushort_t*)alloc((size_t)M_ * D_ * 2);
    ushort_t* wqb = (ushort_t*)alloc((size_t)D_ * D_ * 2);
    ushort_t* wkb = (ushort_t*)alloc((size_t)D_ * D_ * 2);
    ushort_t* wvb = (ushort_t*)alloc((size_t)D_ * D_ * 2);
    ushort_t* wob = (ushort_t*)alloc((size_t)D_ * D_ * 2);
    ushort_t* qhb = (ushort_t*)alloc((size_t)M_ * D_ * 2);  // [B,H,T,DH]
    ushort_t* khb = (ushort_t*)alloc((size_t)M_ * D_ * 2);  // [B,H,T,DH]
    ushort_t* vtb = (ushort_t*)alloc((size_t)M_ * D_ * 2);  // [B,H,DH,T]
    ushort_t* aob = (ushort_t*)alloc((size_t)M_ * D_ * 2);  // [B,T,D]

    cvt_all<<<dim3(4096, 7), 256, 0, stream>>>(q, k, v, wq, wk, wv, wo,
                                               qb, kb, vb, wqb, wkb, wvb, wob);

    gemm_qkv<<<dim3(8, 32, 3), 256, 0, stream>>>(qb, kb, vb, wqb, wkb, wvb, qhb, khb, vtb);

    attn5<<<dim3(1024), 128, 0, stream>>>(qhb, khb, vtb, aob);

    gemm_wo<<<dim3(8, 64), 256, 0, stream>>>(aob, wob, (float*)d_out);
}

// Round 6
// 187.262 us; speedup vs baseline: 1.4610x; 1.4610x over previous
//
#include <hip/hip_runtime.h>
#include <cstdint>
#include <cstddef>

// Problem constants (fixed by the reference)
#define B_  2
#define T_  2048
#define D_  1024
#define H_  16
#define DH_ 64
#define M_  (B_*T_)   // 4096 rows when [B,T,D] flattened

typedef __bf16 bf16x8 __attribute__((ext_vector_type(8)));   // MFMA A/B frag (4 VGPRs)
typedef float  f32x4  __attribute__((ext_vector_type(4)));   // MFMA C/D frag
typedef unsigned short us4 __attribute__((ext_vector_type(4)));
typedef unsigned short us8 __attribute__((ext_vector_type(8)));
typedef unsigned short ushort_t;

__device__ __forceinline__ unsigned short f32_to_bf16_rne(float f) {
    unsigned u = __builtin_bit_cast(unsigned, f);
    u += 0x7FFFu + ((u >> 16) & 1u);
    return (unsigned short)(u >> 16);
}

// pack two f32 -> two bf16 in one u32 (round-half-up). 2 adds + 1 v_perm_b32.
__device__ __forceinline__ unsigned pack_bf16_2(float f0, float f1) {
    unsigned a = __builtin_bit_cast(unsigned, f0) + 0x8000u;
    unsigned b = __builtin_bit_cast(unsigned, f1) + 0x8000u;
    return __builtin_amdgcn_perm(b, a, 0x07060302u);   // (hi16(b)<<16) | hi16(a)
}

// async global->LDS, 16 B per lane. HW rule: LDS dest = wave-uniform base + lane*16.
// Global source is per-lane free: used for XOR chunk swizzles and key-row perms.
__device__ __forceinline__ void async16(const void* g, void* l) {
    __builtin_amdgcn_global_load_lds(
        (const __attribute__((address_space(1))) unsigned int*)(uintptr_t)g,
        (__attribute__((address_space(3))) unsigned int*)(uintptr_t)l, 16, 0, 0);
}

// ---------------- fp32 -> bf16 conversion (single launch, 7 tensors) ----------------
__global__ __launch_bounds__(256) void cvt_all(
    const float* __restrict__ i0, const float* __restrict__ i1, const float* __restrict__ i2,
    const float* __restrict__ i3, const float* __restrict__ i4, const float* __restrict__ i5,
    const float* __restrict__ i6,
    ushort_t* __restrict__ o0, ushort_t* __restrict__ o1, ushort_t* __restrict__ o2,
    ushort_t* __restrict__ o3, ushort_t* __restrict__ o4, ushort_t* __restrict__ o5,
    ushort_t* __restrict__ o6) {
    const int y = blockIdx.y;
    const float* in = y == 0 ? i0 : y == 1 ? i1 : y == 2 ? i2 : y == 3 ? i3
                    : y == 4 ? i4 : y == 5 ? i5 : i6;
    ushort_t* out  = y == 0 ? o0 : y == 1 ? o1 : y == 2 ? o2 : y == 3 ? o3
                    : y == 4 ? o4 : y == 5 ? o5 : o6;
    const int n = (y < 3) ? (M_ * D_) : (D_ * D_);
    int i = (blockIdx.x * 256 + threadIdx.x) * 4;
    if (i >= n) return;
    float4 f = *reinterpret_cast<const float4*>(in + i);
    unsigned lo = pack_bf16_2(f.x, f.y);
    unsigned hi = pack_bf16_2(f.z, f.w);
    *reinterpret_cast<unsigned long long*>(out + i) =
        (unsigned long long)lo | ((unsigned long long)hi << 32);
}

// ---------------- NT GEMM mainloop: BK=64, swizzled staging, 128x128 tile ----------------
__device__ __forceinline__ void gemm_mainloop(const ushort_t* __restrict__ A,
                                              const ushort_t* __restrict__ W,
                                              ushort_t* As, ushort_t* Bs,
                                              int m0, int n0, f32x4 acc[4][4]) {
    const int tid  = threadIdx.x;
    const int lc   = tid & 15;
    const int quad = (tid >> 4) & 3;
    const int wave = tid >> 6;
    const int wm = (wave >> 1) * 64, wn = (wave & 1) * 64;
    const int sw = lc & 7;   // row-derived swizzle (row&7 == lc&7 for frag rows)

    const f32x4 fzero = {0.f, 0.f, 0.f, 0.f};
#pragma unroll
    for (int mt = 0; mt < 4; ++mt)
#pragma unroll
        for (int nt = 0; nt < 4; ++nt) acc[mt][nt] = fzero;

    for (int kk = 0; kk < D_; kk += 64) {
        __syncthreads();
#pragma unroll
        for (int i = 0; i < 4; ++i) {
            const int j = i * 256 + tid;           // 1024 chunks of 16 B per tile
            const int r = j >> 3, c = (j & 7) ^ (r & 7);
            async16(A + (size_t)(m0 + r) * D_ + kk + c * 8, As + j * 8);
            async16(W + (size_t)(n0 + r) * D_ + kk + c * 8, Bs + j * 8);
        }
        __syncthreads();   // staging complete
#pragma unroll
        for (int ks = 0; ks < 2; ++ks) {
            bf16x8 af[4], bw[4];
#pragma unroll
            for (int mt = 0; mt < 4; ++mt)
                af[mt] = *reinterpret_cast<const bf16x8*>(
                    As + (wm + mt * 16 + lc) * 64 + (((ks * 4 + quad) ^ sw) * 8));
#pragma unroll
            for (int nt = 0; nt < 4; ++nt)
                bw[nt] = *reinterpret_cast<const bf16x8*>(
                    Bs + (wn + nt * 16 + lc) * 64 + (((ks * 4 + quad) ^ sw) * 8));
#pragma unroll
            for (int mt = 0; mt < 4; ++mt)
#pragma unroll
                for (int nt = 0; nt < 4; ++nt)
                    acc[mt][nt] = __builtin_amdgcn_mfma_f32_16x16x32_bf16(af[mt], bw[nt], acc[mt][nt], 0, 0, 0);
        }
    }
}

// Fused Q/K/V projection: grid (8, 32, 3). XCD-local remap.
__global__ __launch_bounds__(256, 3) void gemm_qkv(
    const ushort_t* __restrict__ qb, const ushort_t* __restrict__ kb, const ushort_t* __restrict__ vb,
    const ushort_t* __restrict__ wqb, const ushort_t* __restrict__ wkb, const ushort_t* __restrict__ wvb,
    ushort_t* __restrict__ qhb, ushort_t* __restrict__ khb, ushort_t* __restrict__ vtb) {
    __shared__ __align__(16) ushort_t As[128 * 64];
    __shared__ __align__(16) ushort_t Bs[128 * 64];
    __shared__ __align__(16) ushort_t Ts[4][16 * 80];   // per-wave epilogue relayout

    const int z = blockIdx.z;
    const ushort_t* A = z == 0 ? qb : z == 1 ? kb : vb;
    const ushort_t* W = z == 0 ? wqb : z == 1 ? wkb : wvb;
    const int yt = blockIdx.x + 8 * (blockIdx.y >> 3);   // A-tile (XCD-local)
    const int xt = blockIdx.y & 7;                       // W-col tile
    const int m0 = yt * 128, n0 = xt * 128;

    f32x4 acc[4][4];
    gemm_mainloop(A, W, As, Bs, m0, n0, acc);

    const int tid = threadIdx.x, lane = tid & 63, lc = tid & 15;
    const int quad = (tid >> 4) & 3, wave = tid >> 6;
    const int wm = (wave >> 1) * 64, wn = (wave & 1) * 64;
    const int mG = m0 + wm;
    const int bb = mG >> 11, t0 = mG & (T_ - 1);
    const int hh = (n0 + wn) >> 6;   // wave n-range = exactly one head

    if (z < 2) {
        ushort_t* outp = (z == 0 ? qhb : khb) + ((size_t)bb * H_ + hh) * T_ * DH_;
#pragma unroll
        for (int mt = 0; mt < 4; ++mt) {
#pragma unroll
            for (int nt = 0; nt < 4; ++nt)
#pragma unroll
                for (int r = 0; r < 4; ++r)
                    Ts[wave][(quad * 4 + r) * 80 + nt * 16 + lc] = f32_to_bf16_rne(acc[mt][nt][r]);
#pragma unroll
            for (int it = 0; it < 2; ++it) {
                const int c = it * 64 + lane;   // 128 chunks of 16 B
                const int row = c >> 3, c8 = c & 7;
                us8 vv = *reinterpret_cast<const us8*>(Ts[wave] + row * 80 + c8 * 8);
                *reinterpret_cast<us8*>(outp + (size_t)(t0 + mt * 16 + row) * DH_ + c8 * 8) = vv;
            }
        }
    } else {
        // V^T store [B,H,DH,T]
        ushort_t* base = vtb + ((size_t)bb * H_ + hh) * DH_ * T_;
#pragma unroll
        for (int mt = 0; mt < 4; ++mt) {
#pragma unroll
            for (int nt = 0; nt < 4; ++nt)
#pragma unroll
                for (int r = 0; r < 4; ++r)
                    Ts[wave][(nt * 16 + lc) * 16 + quad * 4 + r] = f32_to_bf16_rne(acc[mt][nt][r]);
#pragma unroll
            for (int it = 0; it < 2; ++it) {
                const int c = it * 64 + lane;
                const int nl = c >> 1, mh = c & 1;
                us8 vv = *reinterpret_cast<const us8*>(Ts[wave] + c * 8);
                *reinterpret_cast<us8*>(base + (size_t)nl * T_ + t0 + mt * 16 + mh * 8) = vv;
            }
        }
    }
}

// Final projection: 64x128 tiles, grid (8,64) -> 512 blocks (2/CU), fp32 out.
__global__ __launch_bounds__(256, 4) void gemm_wo(const ushort_t* __restrict__ A,
                                                  const ushort_t* __restrict__ W,
                                                  float* __restrict__ out) {
    __shared__ __align__(16) ushort_t As[64 * 64];
    __shared__ __align__(16) ushort_t Bs[128 * 64];
    const int yt = blockIdx.x + 8 * (blockIdx.y >> 3);   // 64 A-tiles, XCD-local
    const int xt = blockIdx.y & 7;
    const int m0 = yt * 64, n0 = xt * 128;

    const int tid = threadIdx.x, lc = tid & 15;
    const int quad = (tid >> 4) & 3, wave = tid >> 6;
    const int wm = (wave >> 1) * 32, wn = (wave & 1) * 64;
    const int sw = lc & 7;

    const f32x4 fzero = {0.f, 0.f, 0.f, 0.f};
    f32x4 acc[2][4];
#pragma unroll
    for (int mt = 0; mt < 2; ++mt)
#pragma unroll
        for (int nt = 0; nt < 4; ++nt) acc[mt][nt] = fzero;

    for (int kk = 0; kk < D_; kk += 64) {
        __syncthreads();
#pragma unroll
        for (int i = 0; i < 2; ++i) {
            const int j = i * 256 + tid;           // 512 chunks (A: 64 rows)
            const int r = j >> 3, c = (j & 7) ^ (r & 7);
            async16(A + (size_t)(m0 + r) * D_ + kk + c * 8, As + j * 8);
        }
#pragma unroll
        for (int i = 0; i < 4; ++i) {
            const int j = i * 256 + tid;           // 1024 chunks (B: 128 rows)
            const int r = j >> 3, c = (j & 7) ^ (r & 7);
            async16(W + (size_t)(n0 + r) * D_ + kk + c * 8, Bs + j * 8);
        }
        __syncthreads();
#pragma unroll
        for (int ks = 0; ks < 2; ++ks) {
            bf16x8 af[2], bw[4];
#pragma unroll
            for (int mt = 0; mt < 2; ++mt)
                af[mt] = *reinterpret_cast<const bf16x8*>(
                    As + (wm + mt * 16 + lc) * 64 + (((ks * 4 + quad) ^ sw) * 8));
#pragma unroll
            for (int nt = 0; nt < 4; ++nt)
                bw[nt] = *reinterpret_cast<const bf16x8*>(
                    Bs + (wn + nt * 16 + lc) * 64 + (((ks * 4 + quad) ^ sw) * 8));
#pragma unroll
            for (int mt = 0; mt < 2; ++mt)
#pragma unroll
                for (int nt = 0; nt < 4; ++nt)
                    acc[mt][nt] = __builtin_amdgcn_mfma_f32_16x16x32_bf16(af[mt], bw[nt], acc[mt][nt], 0, 0, 0);
        }
    }

#pragma unroll
    for (int mt = 0; mt < 2; ++mt)
#pragma unroll
        for (int nt = 0; nt < 4; ++nt)
#pragma unroll
            for (int r = 0; r < 4; ++r) {
                const int m = m0 + wm + mt * 16 + quad * 4 + r;
                const int n = n0 + wn + nt * 16 + lc;
                out[(size_t)m * D_ + n] = acc[mt][nt][r];
            }
}

// ---------------- causal flash attention v6 ----------------
// attn4 structure (staged LDS K/V, 2 k-groups x 2 waves x 32 Q rows, key-permuted K,
// packed b64 P writes) with SINGLE-buffered K/V: LDS 41 KB -> 3 blocks/CU (was 76.8
// KB -> 2). Cross-block overlap covers the staging drain (m97/m99/m100 evidence).
// Grid 1024, true LPT: qt descending is the OUTER dispatch dim (longest blocks first),
// XCD-pinned bh (4 bh per XCD keeps K/V in the 4 MB per-XCD L2 — round-4 FETCH proof).
__global__ __launch_bounds__(256, 3) void attn6(const ushort_t* __restrict__ Qh,
                                                const ushort_t* __restrict__ Kh,
                                                const ushort_t* __restrict__ Vt,
                                                ushort_t* __restrict__ Ao) {
    // K: 2 tiles x 4096 ush | V: 2 tiles | P: 4 waves x 16 rows x stride 72
    __shared__ __align__(16) ushort_t smem[16384 + 4 * 16 * 72];   // 41 KB

    const int tid = threadIdx.x, lane = tid & 63, lc = tid & 15;
    const int quad = (tid >> 4) & 3, wave = tid >> 6;   // 0..3
    const int grp = wave >> 1, sub = wave & 1;
    const int sw = lc & 7;

    const int L = blockIdx.x;
    const int xcd = L & 7, s = L >> 3;       // s in 0..127
    const int qt = 31 - (s >> 2);            // OUTER: longest q-tiles dispatched first
    const int bh = xcd + 8 * (s & 3);        // 4 bh per XCD
    const int bb = bh >> 4, hh = bh & 15;
    const int q0 = qt * 64, nkt = qt + 1;
    const int nIt = (nkt + 1) >> 1;
    const int mbase = q0 + sub * 32;

    const ushort_t* Qp = Qh + (size_t)bh * T_ * DH_;
    const ushort_t* Kp = Kh + (size_t)bh * T_ * DH_;
    const ushort_t* Vp = Vt + (size_t)bh * DH_ * T_;
    const float SC2 = 0.18033688f;   // log2(e)/sqrt(64)
    const f32x4 fzero = {0.f, 0.f, 0.f, 0.f};
    ushort_t* Pw = smem + 16384 + wave * (16 * 72);

    // Q A-frags (32 rows -> 2 m-tiles), loop-invariant
    bf16x8 aq[2][2];
#pragma unroll
    for (int mt = 0; mt < 2; ++mt) {
        const ushort_t* qrow = Qp + (size_t)(mbase + mt * 16 + lc) * DH_ + quad * 8;
        aq[mt][0] = *reinterpret_cast<const bf16x8*>(qrow);
        aq[mt][1] = *reinterpret_cast<const bf16x8*>(qrow + 32);
    }

    f32x4 o[2][4];
    float lsum[2][4];
#pragma unroll
    for (int mt = 0; mt < 2; ++mt) {
#pragma unroll
        for (int ct = 0; ct < 4; ++ct) o[mt][ct] = fzero;
#pragma unroll
        for (int r = 0; r < 4; ++r) lsum[mt][r] = 0.f;
    }

    for (int it = 0; it < nIt; ++it) {
        const int kt0 = 2 * it;
        __syncthreads();   // previous iteration's frag reads complete (overwrite-safe)
#pragma unroll
        for (int i = 0; i < 2; ++i) {
            const int j = i * 256 + tid;   // 512 chunks per 8 KB tile
            const int r = j >> 3, c = (j & 7) ^ (r & 7);
            const int kprm = 4 * (r & 15) + (r >> 4);   // K key-row permutation
            async16(Kp + (size_t)(kt0 * 64 + kprm) * DH_ + c * 8, smem + j * 8);
            async16(Vp + (size_t)r * T_ + kt0 * 64 + c * 8,       smem + 8192 + j * 8);
            if (kt0 + 1 < nkt) {
                async16(Kp + (size_t)((kt0 + 1) * 64 + kprm) * DH_ + c * 8, smem + 4096 + j * 8);
                async16(Vp + (size_t)r * T_ + (kt0 + 1) * 64 + c * 8,       smem + 12288 + j * 8);
            }
        }
        __syncthreads();   // staging complete (drains vmcnt)

        const int kt = kt0 + grp;
        if (kt < nkt) {
            const int k0 = kt * 64;
            const ushort_t* Kt    = smem + grp * 4096;
            const ushort_t* Vtile = smem + 8192 + grp * 4096;

            // ---- V B-frags once (shared across both m-tiles) ----
            bf16x8 bv[4][2];
#pragma unroll
            for (int ct = 0; ct < 4; ++ct) {
                const ushort_t* vr = Vtile + (ct * 16 + lc) * 64;
                bv[ct][0] = *reinterpret_cast<const bf16x8*>(vr + ((quad ^ sw) * 8));
                bv[ct][1] = *reinterpret_cast<const bf16x8*>(vr + (((4 + quad) ^ sw) * 8));
            }

            // ---- S = Q K^T (K frags shared across m-tiles) ----
            f32x4 sc[2][4];
#pragma unroll
            for (int ct = 0; ct < 4; ++ct) {
                const ushort_t* kr = Kt + (ct * 16 + lc) * 64;
                bf16x8 bk0 = *reinterpret_cast<const bf16x8*>(kr + ((quad ^ sw) * 8));
                bf16x8 bk1 = *reinterpret_cast<const bf16x8*>(kr + (((4 + quad) ^ sw) * 8));
#pragma unroll
                for (int mt = 0; mt < 2; ++mt) {
                    sc[mt][ct] = __builtin_amdgcn_mfma_f32_16x16x32_bf16(aq[mt][0], bk0, fzero, 0, 0, 0);
                    sc[mt][ct] = __builtin_amdgcn_mfma_f32_16x16x32_bf16(aq[mt][1], bk1, sc[mt][ct], 0, 0, 0);
                }
            }

            // ---- per m-tile: fixed-max softmax -> packed P write -> PV ----
#pragma unroll
            for (int mt = 0; mt < 2; ++mt) {
                float e[4][4];
                if (kt == qt) {   // only the diagonal tile masks
#pragma unroll
                    for (int ct = 0; ct < 4; ++ct) {
                        const int key = k0 + 4 * lc + ct;   // permuted key of this col
#pragma unroll
                        for (int r = 0; r < 4; ++r) {
                            const int row = mbase + mt * 16 + quad * 4 + r;
                            e[ct][r] = (key <= row) ? __builtin_amdgcn_exp2f(sc[mt][ct][r] * SC2) : 0.f;
                        }
                    }
                } else {
#pragma unroll
                    for (int ct = 0; ct < 4; ++ct)
#pragma unroll
                        for (int r = 0; r < 4; ++r)
                            e[ct][r] = __builtin_amdgcn_exp2f(sc[mt][ct][r] * SC2);
                }
#pragma unroll
                for (int r = 0; r < 4; ++r) {
                    lsum[mt][r] += (e[0][r] + e[1][r]) + (e[2][r] + e[3][r]);
                    unsigned lo = pack_bf16_2(e[0][r], e[1][r]);
                    unsigned hi = pack_bf16_2(e[2][r], e[3][r]);
                    *reinterpret_cast<unsigned long long*>(Pw + (quad * 4 + r) * 72 + lc * 4) =
                        (unsigned long long)lo | ((unsigned long long)hi << 32);
                }
                bf16x8 ap0 = *reinterpret_cast<const bf16x8*>(Pw + lc * 72 + quad * 8);
                bf16x8 ap1 = *reinterpret_cast<const bf16x8*>(Pw + lc * 72 + 32 + quad * 8);
#pragma unroll
                for (int ct = 0; ct < 4; ++ct) {
                    o[mt][ct] = __builtin_amdgcn_mfma_f32_16x16x32_bf16(ap0, bv[ct][0], o[mt][ct], 0, 0, 0);
                    o[mt][ct] = __builtin_amdgcn_mfma_f32_16x16x32_bf16(ap1, bv[ct][1], o[mt][ct], 0, 0, 0);
                }
            }
        }
    }

    // ---- combine the two k-groups via LDS; group 1 normalizes + stores ----
    __syncthreads();   // compute done; K/V LDS reusable as scratch
    float* Osh = (float*)smem;             // 16 KB (K region)
    float* Lsh = (float*)(smem + 8192);    // 4 KB (V region)
    if (grp == 0) {
#pragma unroll
        for (int mt = 0; mt < 2; ++mt) {
#pragma unroll
            for (int ct = 0; ct < 4; ++ct)
#pragma unroll
                for (int r = 0; r < 4; ++r)
                    Osh[(sub * 32 + mt * 16 + quad * 4 + r) * 64 + ct * 16 + lc] = o[mt][ct][r];
#pragma unroll
            for (int r = 0; r < 4; ++r)
                Lsh[(sub * 32 + mt * 16 + quad * 4 + r) * 16 + lc] = lsum[mt][r];
        }
    }
    __syncthreads();
    if (grp == 1) {
#pragma unroll
        for (int mt = 0; mt < 2; ++mt) {
            float inv[4];
#pragma unroll
            for (int r = 0; r < 4; ++r) {
                float l = lsum[mt][r] + Lsh[(sub * 32 + mt * 16 + quad * 4 + r) * 16 + lc];
#pragma unroll
                for (int d = 1; d < 16; d <<= 1) l += __shfl_xor(l, d);
                inv[r] = 1.0f / l;
            }
#pragma unroll
            for (int ct = 0; ct < 4; ++ct)
#pragma unroll
                for (int r = 0; r < 4; ++r) {
                    const int rowq = mbase + mt * 16 + quad * 4 + r;
                    const float ov = o[mt][ct][r] +
                        Osh[(sub * 32 + mt * 16 + quad * 4 + r) * 64 + ct * 16 + lc];
                    Ao[((size_t)bb * T_ + rowq) * D_ + hh * DH_ + ct * 16 + lc] =
                        f32_to_bf16_rne(ov * inv[r]);
                }
        }
    }
}

// ---------------- launch ----------------
extern "C" void kernel_launch(void* const* d_in, const int* in_sizes, int n_in,
                              void* d_out, int out_size, void* d_ws, size_t ws_size,
                              hipStream_t stream) {
    const float* q  = (const float*)d_in[0];
    const float* k  = (const float*)d_in[1];
    const float* v  = (const float*)d_in[2];
    const float* wq = (const float*)d_in[3];
    const float* wk = (const float*)d_in[4];
    const float* wv = (const float*)d_in[5];
    const float* wo = (const float*)d_in[6];

    char* ws = (char*)d_ws;
    size_t off = 0;
    auto alloc = [&](size_t bytes) -> char* {
        char* p = ws + off;
        off += (bytes + 255) & ~(size_t)255;
        return p;
    };
    ushort_t* qb  = (ushort_t*)alloc((size_t)M_ * D_ * 2);
    ushort_t* kb  = (ushort_t*)alloc((size_t)M_ * D_ * 2);
    ushort_t* vb  = (ushort_t*)alloc((size_t)M_ * D_ * 2);
    ushort_t* wqb = (ushort_t*)alloc((size_t)D_ * D_ * 2);
    ushort_t* wkb = (ushort_t*)alloc((size_t)D_ * D_ * 2);
    ushort_t* wvb = (ushort_t*)alloc((size_t)D_ * D_ * 2);
    ushort_t* wob = (ushort_t*)alloc((size_t)D_ * D_ * 2);
    ushort_t* qhb = (ushort_t*)alloc((size_t)M_ * D_ * 2);  // [B,H,T,DH]
    ushort_t* khb = (ushort_t*)alloc((size_t)M_ * D_ * 2);  // [B,H,T,DH]
    ushort_t* vtb = (ushort_t*)alloc((size_t)M_ * D_ * 2);  // [B,H,DH,T]
    ushort_t* aob = (ushort_t*)alloc((size_t)M_ * D_ * 2);  // [B,T,D]

    cvt_all<<<dim3(4096, 7), 256, 0, stream>>>(q, k, v, wq, wk, wv, wo,
                                               qb, kb, vb, wqb, wkb, wvb, wob);

    gemm_qkv<<<dim3(8, 32, 3), 256, 0, stream>>>(qb, kb, vb, wqb, wkb, wvb, qhb, khb, vtb);

    attn6<<<dim3(1024), 256, 0, stream>>>(qhb, khb, vtb, aob);

    gemm_wo<<<dim3(8, 64), 256, 0, stream>>>(aob, wob, (float*)d_out);
}